// Round 2
// 648.621 us; speedup vs baseline: 1.1006x; 1.1006x over previous
//
#include <hip/hip_runtime.h>

#define BB 2048
#define LL 1024
#define KK 128
#define DD 64
#define HH 4

// ---------------------------------------------------------------------------
// Fully fused per-batch kernel. One block per batch (2048 blocks x 256 thr).
//   phase A: q = tgt@WQ+bQ ; wkq = WK@q/8 ; sb = q.bK/8     (weights from L2)
//   phase B: gather topk (loads issued at block start, T14), scores, softmax,
//            ctx  (stride-65 LDS: all accesses <=2-way bank alias = free)
//   phase C: heads = ctx@WV+bV ; mhta = heads@WO+bO ; MLP -> logit
// LDS ~39.2 KB -> 4 blocks/CU = 16 waves/CU for every phase (prep/out were
// 4 waves/CU on 128 CUs before). No workspace, no intermediate HBM traffic.
// (Round 1: identical resubmit — round-0 bench died to a container/infra
//  failure with no kernel verdict; audit found no OOB/sync/LDS hazard.)
// ---------------------------------------------------------------------------
__global__ __launch_bounds__(256) void fused_kernel(
    const int* __restrict__ idx, const float* __restrict__ seq,
    const float* __restrict__ tgt,
    const float* __restrict__ WQ, const float* __restrict__ bQ,
    const float* __restrict__ WK, const float* __restrict__ bK,
    const float* __restrict__ WV, const float* __restrict__ bV,
    const float* __restrict__ WO, const float* __restrict__ bO,
    const float* __restrict__ W1, const float* __restrict__ b1,
    const float* __restrict__ W2, const float* __restrict__ b2,
    float* __restrict__ outp)
{
    __shared__ float sTop[KK * 65];   // gathered rows, stride 65 (33280 B)
    __shared__ float sT[DD];          // target emb
    __shared__ float sA[256];         // q  -> later heads
    __shared__ float sB[256];         // wkq -> WO partials -> MLP partials
    __shared__ float sSc[HH * KK];    // scores -> attn (in place)
    __shared__ float sCtx[256];       // attention context
    __shared__ float sX[2 * DD];      // MLP input [mhta | tgt]
    __shared__ float sSb[HH];

    const int t = threadIdx.x;
    const int b = blockIdx.x;
    const int h = t >> 6, e = t & 63;
    const int w = t >> 6, lane = t & 63;

    // ---- issue gather EARLY, hold in registers (hide HBM latency under
    //      the projection compute). thread t owns rows r0+16j, cols c0..c0+3.
    const int r0 = t >> 4;            // 0..15
    const int c0 = (t & 15) * 4;
    int rows[8];
    #pragma unroll
    for (int j = 0; j < 8; j++) rows[j] = idx[b * KK + r0 + 16 * j];
    float4 g[8];
    #pragma unroll
    for (int j = 0; j < 8; j++)
        g[j] = *(const float4*)(seq + ((size_t)b * LL + rows[j]) * DD + c0);

    if (t < DD) sT[t] = tgt[(size_t)b * DD + t];
    __syncthreads();

    // ---- q[h][e] = bQ + sum_d tgt[d] * WQ[h][d][e]  (wave-coalesced 256B)
    float q = bQ[t];
    #pragma unroll 8
    for (int d = 0; d < DD; d++)
        q += sT[d] * WQ[((h << 6) + d) * 64 + e];
    sA[t] = q;

    // ---- sb[h] = (q . bK[h]) / 8
    {
        float p = q * bK[t];
        #pragma unroll
        for (int o = 32; o > 0; o >>= 1) p += __shfl_xor(p, o);
        if (e == 0) sSb[h] = p * 0.125f;
    }
    __syncthreads();

    // ---- wkq[t=(h,d)] = (sum_e WK[h][d][e] * q[h][e]) / 8 ; row streamed f4
    {
        float acc2 = 0.f;
        const float* wrow = WK + (size_t)t * 64;
        #pragma unroll 4
        for (int i = 0; i < 64; i += 4) {
            float4 w4 = *(const float4*)(wrow + i);
            acc2 += w4.x * sA[(h << 6) + i]     + w4.y * sA[(h << 6) + i + 1]
                  + w4.z * sA[(h << 6) + i + 2] + w4.w * sA[(h << 6) + i + 3];
        }
        sB[t] = acc2 * 0.125f;
    }

    // ---- drain gather into LDS (compiler inserts the vmcnt wait here)
    #pragma unroll
    for (int j = 0; j < 8; j++) {
        float* dst = &sTop[(r0 + 16 * j) * 65 + c0];
        dst[0] = g[j].x; dst[1] = g[j].y; dst[2] = g[j].z; dst[3] = g[j].w;
    }
    __syncthreads();

    // ---- scores: 512 outputs, 2/thread; bank pattern (k+d)%32 -> free
    #pragma unroll
    for (int s = 0; s < 2; s++) {
        int id = (s << 8) + t;
        int hh = id >> 7, k = id & 127;
        float a = 0.f;
        #pragma unroll 8
        for (int d = 0; d < DD; d++)
            a += sTop[k * 65 + d] * sB[(hh << 6) + d];
        sSc[(hh << 7) + k] = a + sSb[hh];
    }
    __syncthreads();

    // ---- softmax: wave w = head w (128 scores = 2/lane), in place
    {
        float x0 = sSc[(w << 7) + lane], x1 = sSc[(w << 7) + 64 + lane];
        float m = fmaxf(x0, x1);
        #pragma unroll
        for (int o = 32; o > 0; o >>= 1) m = fmaxf(m, __shfl_xor(m, o));
        float e0 = __expf(x0 - m), e1 = __expf(x1 - m);
        float s = e0 + e1;
        #pragma unroll
        for (int o = 32; o > 0; o >>= 1) s += __shfl_xor(s, o);
        float inv = 1.f / s;
        sSc[(w << 7) + lane] = e0 * inv;
        sSc[(w << 7) + 64 + lane] = e1 * inv;
    }
    __syncthreads();

    // ---- ctx[h=w][d=lane] = sum_k attn[k] * topk[k][d]
    {
        float cacc = 0.f;
        #pragma unroll 8
        for (int k = 0; k < KK; k++)
            cacc += sSc[(w << 7) + k] * sTop[k * 65 + lane];
        sCtx[t] = cacc;
    }
    __syncthreads();

    // ---- heads[h][e] = bV + sum_d ctx[h][d] * WV[h][d][e]
    {
        float hv = bV[t];
        #pragma unroll 8
        for (int d = 0; d < DD; d++)
            hv += sCtx[(h << 6) + d] * WV[((h << 6) + d) * 64 + e];
        sA[t] = hv;
    }
    __syncthreads();

    // ---- WO partials: wave h covers rows [h*64, h*64+64)
    {
        float pa = 0.f;
        #pragma unroll 8
        for (int i = 0; i < 64; i++)
            pa += sA[(h << 6) + i] * WO[((h << 6) + i) * 64 + e];
        sB[t] = pa;
    }
    __syncthreads();

    // ---- mhta + concat with target
    if (t < 64) {
        sX[t] = sB[t] + sB[64 + t] + sB[128 + t] + sB[192 + t] + bO[t];
        sX[64 + t] = sT[t];
    }
    __syncthreads();

    // ---- MLP: wave w covers i in [32w, 32w+32); then wave 0 finishes
    {
        float a1 = 0.f;
        const int i0 = w << 5;
        #pragma unroll 8
        for (int i = i0; i < i0 + 32; i++)
            a1 += sX[i] * W1[i * 64 + lane];
        sB[(w << 6) + lane] = a1;
    }
    __syncthreads();
    if (t < 64) {
        float v = sB[t] + sB[64 + t] + sB[128 + t] + sB[192 + t] + b1[t];
        v = fmaxf(v, 0.f);
        float p = v * W2[t];
        #pragma unroll
        for (int o = 32; o > 0; o >>= 1) p += __shfl_xor(p, o);
        if (t == 0) outp[b] = p + b2[0];
    }
}

extern "C" void kernel_launch(void* const* d_in, const int* in_sizes, int n_in,
                              void* d_out, int out_size, void* d_ws, size_t ws_size,
                              hipStream_t stream)
{
    const int*   idx = (const int*)d_in[0];
    const float* seq = (const float*)d_in[1];
    const float* tgt = (const float*)d_in[2];
    const float* WQ  = (const float*)d_in[3];
    const float* bQ  = (const float*)d_in[4];
    const float* WK  = (const float*)d_in[5];
    const float* bK  = (const float*)d_in[6];
    const float* WV  = (const float*)d_in[7];
    const float* bV  = (const float*)d_in[8];
    const float* WO  = (const float*)d_in[9];
    const float* bO  = (const float*)d_in[10];
    const float* W1  = (const float*)d_in[11];
    const float* b1  = (const float*)d_in[12];
    const float* W2  = (const float*)d_in[13];
    const float* b2  = (const float*)d_in[14];
    float* outp = (float*)d_out;

    fused_kernel<<<dim3(BB), dim3(256), 0, stream>>>(
        idx, seq, tgt, WQ, bQ, WK, bK, WV, bV, WO, bO, W1, b1, W2, b2, outp);
}

// Round 4
// 633.043 us; speedup vs baseline: 1.1277x; 1.0246x over previous
//
#include <hip/hip_runtime.h>

#define BB 2048
#define LL 1024
#define KK 128
#define DD 64
#define HH 4

// wave-uniform broadcast from lane l (COMPILE-TIME CONSTANT l only) via
// v_readlane on the VALU pipe, NOT the LDS pipe.
__device__ __forceinline__ float rl(float v, int l) {
    return __int_as_float(__builtin_amdgcn_readlane(__float_as_int(v), l));
}

// ---------------------------------------------------------------------------
// Fully fused per-batch kernel, LDS-pipe-minimized.
// Wave w owns head w end-to-end; per-head vectors (q, wkq, attn, ctx, heads)
// live distributed across the wave's lanes and are broadcast with v_readlane
// using LITERAL lane indices (all such loops fully unrolled — round-3
// hardening: runtime lane operands on readlane removed; MLP x[] broadcast
// moved to uniform-address LDS reads).
// sTop: row stride 64 dwords with XOR chunk swizzle  elem(k,d) -> dword
// (k<<6) | (((d>>2)^(k&7))<<2) | (d&3):
//   - drain writes (float4)    : conflict-free
//   - scores row ds_read_b128  : conflict-free
//   - ctx column b32 reads     : 2-way (free)
// DS ops/thread ~800 (r2 baseline) -> ~220.  4 barriers.
// ---------------------------------------------------------------------------
__global__ __launch_bounds__(256, 4) void fused_kernel(
    const int* __restrict__ idx, const float* __restrict__ seq,
    const float* __restrict__ tgt,
    const float* __restrict__ WQ, const float* __restrict__ bQ,
    const float* __restrict__ WK, const float* __restrict__ bK,
    const float* __restrict__ WV, const float* __restrict__ bV,
    const float* __restrict__ WO, const float* __restrict__ bO,
    const float* __restrict__ W1, const float* __restrict__ b1,
    const float* __restrict__ W2, const float* __restrict__ b2,
    float* __restrict__ outp)
{
    __shared__ float sTop[KK * 64];   // 32 KB, swizzled (see header comment)
    __shared__ float sP[256];         // cross-wave partial exchange
    __shared__ float sX[2 * DD];      // MLP input [mhta | tgt]

    const int t = threadIdx.x;
    const int b = blockIdx.x;
    const int w = t >> 6, lane = t & 63;

    // ---- issue gather EARLY (T14): thread t owns rows r0+16j, cols c0..c0+3
    const int r0 = t >> 4;            // 0..15
    const int c0 = (t & 15) << 2;     // 0,4,...,60
    int rows[8];
    #pragma unroll
    for (int j = 0; j < 8; j++) rows[j] = idx[b * KK + r0 + 16 * j];
    float4 g[8];
    #pragma unroll
    for (int j = 0; j < 8; j++)
        g[j] = *(const float4*)(seq + ((size_t)b * LL + rows[j]) * DD + c0);

    const float tg = tgt[(size_t)b * DD + lane];

    // ---- q[w][lane] = bQ + sum_d tgt[d] * WQ[w][d][lane]  (wave-coalesced)
    float q = bQ[t];
    #pragma unroll
    for (int d = 0; d < DD; d++)
        q += rl(tg, d) * WQ[((w << 6) + d) * 64 + lane];

    // ---- sb[w] = (q . bK[w]) / 8  (uniform in all lanes after butterfly)
    float p = q * bK[t];
    #pragma unroll
    for (int o = 32; o > 0; o >>= 1) p += __shfl_xor(p, o);
    const float sb = p * 0.125f;

    // ---- wkq[w][lane] = (sum_e WK[w][lane][e] * q[w][e]) / 8
    float wk = 0.f;
    {
        const float* wrow = WK + (size_t)t * 64;
        #pragma unroll
        for (int i = 0; i < 16; i++) {
            float4 w4 = *(const float4*)(wrow + 4 * i);
            wk += w4.x * rl(q, 4 * i)     + w4.y * rl(q, 4 * i + 1)
                + w4.z * rl(q, 4 * i + 2) + w4.w * rl(q, 4 * i + 3);
        }
        wk *= 0.125f;
    }

    // ---- drain gather into swizzled sTop (conflict-free float4 writes)
    #pragma unroll
    for (int j = 0; j < 8; j++) {
        int r = r0 + 16 * j;
        *(float4*)&sTop[(r << 6) + (((c0 >> 2) ^ (r & 7)) << 2)] = g[j];
    }
    __syncthreads();   // B1

    // ---- scores: lane computes k=lane and k=64+lane for head w
    //      conflict-free ds_read_b128 row reads; wkq via constant readlane
    float acc0 = 0.f, acc1 = 0.f;
    {
        const int ra = lane << 6;
        const int rb = (64 + lane) << 6;          // (64+lane)&7 == lane&7
        const int rx = lane & 7;
        #pragma unroll
        for (int i = 0; i < 16; i++) {
            const float4 va = *(const float4*)&sTop[ra + ((i ^ rx) << 2)];
            const float4 vb = *(const float4*)&sTop[rb + ((i ^ rx) << 2)];
            const float s0 = rl(wk, 4 * i),     s1 = rl(wk, 4 * i + 1);
            const float s2 = rl(wk, 4 * i + 2), s3 = rl(wk, 4 * i + 3);
            acc0 += s0 * va.x + s1 * va.y + s2 * va.z + s3 * va.w;
            acc1 += s0 * vb.x + s1 * vb.y + s2 * vb.z + s3 * vb.w;
        }
    }
    const float x0 = acc0 + sb, x1 = acc1 + sb;

    // ---- softmax fully in registers (wave w = head w)
    float m = fmaxf(x0, x1);
    #pragma unroll
    for (int o = 32; o > 0; o >>= 1) m = fmaxf(m, __shfl_xor(m, o));
    const float e0 = __expf(x0 - m), e1 = __expf(x1 - m);
    float sden = e0 + e1;
    #pragma unroll
    for (int o = 32; o > 0; o >>= 1) sden += __shfl_xor(sden, o);
    const float inv = 1.f / sden;
    const float a0 = e0 * inv, a1 = e1 * inv;

    // ---- ctx[w][lane] = sum_k attn[k] * topk[k][lane]
    //      column b32 reads (2-way, free); attn via constant readlane
    float ctx = 0.f;
    {
        int cbase[8];
        #pragma unroll
        for (int c = 0; c < 8; c++)
            cbase[c] = ((((lane >> 2) ^ c) << 2) + (lane & 3));
        #pragma unroll
        for (int k = 0; k < KK; k++) {
            const float ak = (k < 64) ? rl(a0, k) : rl(a1, k - 64);
            ctx += ak * sTop[(k << 6) + cbase[k & 7]];
        }
    }

    // ---- heads[w][lane] = bV + sum_d ctx[w][d] * WV[w][d][lane]
    float hv = bV[t];
    #pragma unroll
    for (int d = 0; d < DD; d++)
        hv += rl(ctx, d) * WV[((w << 6) + d) * 64 + lane];

    // ---- WO partials: wave w covers rows [w*64, w*64+64)
    float pa = 0.f;
    #pragma unroll
    for (int i = 0; i < DD; i++)
        pa += rl(hv, i) * WO[((w << 6) + i) * 64 + lane];
    sP[t] = pa;
    __syncthreads();   // B2

    // ---- mhta = sum of 4 head-partials + bO ; concat target
    if (t < 64)
        sX[t] = sP[t] + sP[64 + t] + sP[128 + t] + sP[192 + t] + bO[t];
    else if (t < 128)
        sX[64 + (t - 64)] = tg;   // wave 1, lane t-64: tg = tgt[b*64 + t-64]
    __syncthreads();   // B3

    // ---- MLP layer 1: wave w covers i in [32w, 32w+32)
    //      x[i] via uniform-address LDS broadcast (32 DS reads/thread)
    {
        float acc = 0.f;
        const int i0 = w << 5;
        #pragma unroll
        for (int ii = 0; ii < 32; ii++) {
            const int i = i0 + ii;
            acc += sX[i] * W1[i * 64 + lane];
        }
        sP[t] = acc;
    }
    __syncthreads();   // B4

    if (t < 64) {
        float v = sP[t] + sP[64 + t] + sP[128 + t] + sP[192 + t] + b1[t];
        v = fmaxf(v, 0.f);
        float pp = v * W2[t];
        #pragma unroll
        for (int o = 32; o > 0; o >>= 1) pp += __shfl_xor(pp, o);
        if (t == 0) outp[b] = pp + b2[0];
    }
}

extern "C" void kernel_launch(void* const* d_in, const int* in_sizes, int n_in,
                              void* d_out, int out_size, void* d_ws, size_t ws_size,
                              hipStream_t stream)
{
    const int*   idx = (const int*)d_in[0];
    const float* seq = (const float*)d_in[1];
    const float* tgt = (const float*)d_in[2];
    const float* WQ  = (const float*)d_in[3];
    const float* bQ  = (const float*)d_in[4];
    const float* WK  = (const float*)d_in[5];
    const float* bK  = (const float*)d_in[6];
    const float* WV  = (const float*)d_in[7];
    const float* bV  = (const float*)d_in[8];
    const float* WO  = (const float*)d_in[9];
    const float* bO  = (const float*)d_in[10];
    const float* W1  = (const float*)d_in[11];
    const float* b1  = (const float*)d_in[12];
    const float* W2  = (const float*)d_in[13];
    const float* b2  = (const float*)d_in[14];
    float* outp = (float*)d_out;

    fused_kernel<<<dim3(BB), dim3(256), 0, stream>>>(
        idx, seq, tgt, WQ, bQ, WK, bK, WV, bV, WO, bO, W1, b1, W2, b2, outp);
}